// Round 1
// baseline (593.466 us; speedup 1.0000x reference)
//
#include <hip/hip_runtime.h>

#define T_ 4
#define C3 3
#define H_ 128
#define W_ 128
#define XPS 160          // padded image size (128 + 2*16)
#define WSZ 29           // search window
#define K_ 14            // neighbors kept
#define ACCS 132         // H + 2*phalf

// ---------------- kernel 1: per-(t,c) means of normalized image ----------------
__global__ void k_means(const float* __restrict__ noisy, float* __restrict__ means) {
    int tc = blockIdx.x;                       // 0..11
    const float* src = noisy + (size_t)tc * (H_ * W_);
    float s = 0.f;
    for (int i = threadIdx.x; i < H_ * W_; i += 256) s += src[i];
    __shared__ float red[256];
    red[threadIdx.x] = s;
    __syncthreads();
    for (int st = 128; st > 0; st >>= 1) {
        if ((int)threadIdx.x < st) red[threadIdx.x] += red[threadIdx.x + st];
        __syncthreads();
    }
    if (threadIdx.x == 0)
        means[tc] = red[0] * (1.f / (H_ * W_)) * (2.f / 255.f) - 1.f;  // mean of (v/255-0.5)/0.5
}

// ---------------- kernel 2: reflect-pad + normalize + mean-subtract ----------------
// xp layout: [t][160][160][3] channels-last
__global__ void k_pad(const float* __restrict__ noisy, const float* __restrict__ means,
                      float* __restrict__ xp) {
    int idx = blockIdx.x * 256 + threadIdx.x;      // t*160*160 pixel index
    if (idx >= T_ * XPS * XPS) return;
    int t  = idx / (XPS * XPS);
    int rr = (idx / XPS) % XPS;
    int cc = idx % XPS;
    int ry = rr - 16; if (ry < 0) ry = -ry; if (ry > H_ - 1) ry = 2 * (H_ - 1) - ry;
    int rx = cc - 16; if (rx < 0) rx = -rx; if (rx > W_ - 1) rx = 2 * (W_ - 1) - rx;
    float* dst = xp + (size_t)idx * 3;
#pragma unroll
    for (int c = 0; c < 3; c++) {
        float v = noisy[(((size_t)t * 3 + c) * H_ + ry) * W_ + rx];
        dst[c] = v * (2.f / 255.f) - 1.f - means[t * 3 + c];
    }
}

// ---------------- kernel 3: distances + top-14 + softmax + patch scatter ----------------
// one 64-thread block (one wave) per 8x8 pixel tile; LDS tile covers offsets +-14 and patch +-2
__launch_bounds__(64)
__global__ void k_main(const float* __restrict__ xp, const int* __restrict__ sigma_p,
                       float* __restrict__ acc) {
    __shared__ float tile[40][40][3];   // xp rows bi..bi+39, cols bj..bj+39
    __shared__ float e_lds[12][13];     // e field, 12x12 used (+1 pad)
    __shared__ float hs_lds[12][8];     // horizontal 5-sums

    const int lane = threadIdx.x;
    const int b   = blockIdx.x;
    const int t   = b >> 8;
    const int rem = b & 255;
    const int bi  = (rem >> 4) << 3;    // tile pixel-row origin
    const int bj  = (rem & 15) << 3;

    // stage xp tile (40 rows x 120 floats)
    const float* src = xp + ((size_t)(t * XPS + bi) * XPS + bj) * 3;
    float* tf = &tile[0][0][0];
    for (int i = lane; i < 40 * 120; i += 64) {
        int rr = i / 120;
        int cc = i - rr * 120;
        tf[i] = src[(size_t)rr * (XPS * 3) + cc];
    }
    __syncthreads();

    const int ti = lane >> 3, tj = lane & 7;

    // top-14 as packed uint keys: (f32 bits of d & ~0x3FF) | offset-index
    unsigned keys[K_];
#pragma unroll
    for (int k = 0; k < K_; k++) keys[k] = 0xFFFFFF00u + k;   // unique huge sentinels
    unsigned kmax = 0xFFFFFF00u + (K_ - 1);

    // each lane owns up to 3 e-points of the 12x12 field; cache first operand
    float X0[3][3];
    int er[3], ec[3];
#pragma unroll
    for (int q = 0; q < 3; q++) {
        int p  = lane + q * 64;
        int pv = (p < 144) ? p : 0;
        er[q] = pv / 12;
        ec[q] = pv - er[q] * 12;
#pragma unroll
        for (int c = 0; c < 3; c++) X0[q][c] = tile[14 + er[q]][14 + ec[q]][c];
    }

    int o = 0;
    for (int oy = 0; oy < WSZ; oy++) {
        for (int ox = 0; ox < WSZ; ox++, o++) {
            // e(p,q) = || X(p,q) - X(p+dy,q+dx) ||^2  (tile-local: row er+oy, col ec+ox)
#pragma unroll
            for (int q = 0; q < 3; q++) {
                if (lane + q * 64 < 144) {
                    const float* nb = tile[er[q] + oy][ec[q] + ox];
                    float d0 = X0[q][0] - nb[0];
                    float d1 = X0[q][1] - nb[1];
                    float d2 = X0[q][2] - nb[2];
                    e_lds[er[q]][ec[q]] = d0 * d0 + d1 * d1 + d2 * d2;
                }
            }
            __syncthreads();
            // horizontal 5-sum
#pragma unroll
            for (int q = 0; q < 2; q++) {
                int p = lane + q * 64;
                if (p < 96) {
                    int hr = p >> 3, hc = p & 7;
                    const float* e = &e_lds[hr][hc];
                    hs_lds[hr][hc] = e[0] + e[1] + e[2] + e[3] + e[4];
                }
            }
            __syncthreads();
            // vertical 5-sum -> patch distance for this lane's pixel
            float d = hs_lds[ti][tj] + hs_lds[ti + 1][tj] + hs_lds[ti + 2][tj] +
                      hs_lds[ti + 3][tj] + hs_lds[ti + 4][tj];
            unsigned key = (__float_as_uint(d) & 0xFFFFFC00u) | (unsigned)o;
            if (key < kmax) {   // insert: replace current worst, recompute worst
#pragma unroll
                for (int k = 0; k < K_; k++) keys[k] = (keys[k] == kmax) ? key : keys[k];
                kmax = keys[0];
#pragma unroll
                for (int k = 1; k < K_; k++) kmax = keys[k] > kmax ? keys[k] : kmax;
            }
            __syncthreads();   // protect e/hs buffers before next-offset overwrite
        }
    }

    // ---- softmax weights over the 14 kept distances ----
    float sig  = (float)sigma_p[0] * (2.f / 255.f);     // sigma/255/0.5
    float beta = 1.f / (2.f * sig * sig * 75.f);
    float wk[K_];
    int oyk[K_], oxk[K_];
    float dmin = 3.4e38f;
#pragma unroll
    for (int k = 0; k < K_; k++) {
        float dv = __uint_as_float(keys[k] & 0xFFFFFC00u);
        wk[k] = dv;
        int ok = (int)(keys[k] & 1023u);
        oyk[k] = ok / 29;
        oxk[k] = ok - oyk[k] * 29;
        dmin = fminf(dmin, dv);
    }
    float sw = 0.f;
#pragma unroll
    for (int k = 0; k < K_; k++) { float w = __expf(beta * (dmin - wk[k])); wk[k] = w; sw += w; }
    float inv = 1.f / sw;
#pragma unroll
    for (int k = 0; k < K_; k++) wk[k] *= inv;

    // ---- weighted neighbor-patch average, overlap-add scatter ----
    const int gi = bi + ti, gj = bj + tj;
    for (int py = 0; py < 5; py++) {
        for (int px = 0; px < 5; px++) {
            float s0 = 0.f, s1 = 0.f, s2 = 0.f;
#pragma unroll
            for (int k = 0; k < K_; k++) {
                const float* nb = tile[ti + oyk[k] + py][tj + oxk[k] + px];
                s0 += wk[k] * nb[0];
                s1 += wk[k] * nb[1];
                s2 += wk[k] * nb[2];
            }
            float* ap = acc + (((size_t)t * ACCS + (gi + py)) * ACCS + (gj + px)) * 3;
            atomicAdd(ap + 0, s0);
            atomicAdd(ap + 1, s1);
            atomicAdd(ap + 2, s2);
        }
    }
}

// ---------------- kernel 4: normalize by overlap count, un-normalize, write out ----------------
__global__ void k_final(const float* __restrict__ acc, const float* __restrict__ means,
                        float* __restrict__ out) {
    int idx = blockIdx.x * 256 + threadIdx.x;     // [t][ch][i][j]
    if (idx >= T_ * 3 * H_ * W_) return;
    int j  = idx & 127;
    int i  = (idx >> 7) & 127;
    int ch = (idx >> 14) % 3;
    int t  = idx / (3 * H_ * W_);
    int r = i + 2, s = j + 2;
    int ny = (r < 4 ? r : 4) - (r > 127 ? r - 127 : 0) + 1;
    int nx = (s < 4 ? s : 4) - (s > 127 ? s - 127 : 0) + 1;
    float v = acc[(((size_t)t * ACCS + r) * ACCS + s) * 3 + ch] / (float)(ny * nx);
    v += means[t * 3 + ch];
    out[idx] = 127.5f * v + 127.5f;
}

extern "C" void kernel_launch(void* const* d_in, const int* in_sizes, int n_in,
                              void* d_out, int out_size, void* d_ws, size_t ws_size,
                              hipStream_t stream) {
    (void)in_sizes; (void)n_in; (void)out_size; (void)ws_size;
    const float* noisy = (const float*)d_in[0];
    const int*   sigma = (const int*)d_in[1];

    float* means = (float*)d_ws;                         // 12 floats (reserve 64)
    float* xp    = means + 64;                           // 4*160*160*3 floats
    float* acc   = xp + (size_t)T_ * XPS * XPS * 3;      // 4*132*132*3 floats
    float* out   = (float*)d_out;

    hipLaunchKernelGGL(k_means, dim3(12), dim3(256), 0, stream, noisy, means);
    hipLaunchKernelGGL(k_pad, dim3((T_ * XPS * XPS + 255) / 256), dim3(256), 0, stream,
                       noisy, means, xp);
    hipMemsetAsync(acc, 0, (size_t)T_ * ACCS * ACCS * 3 * sizeof(float), stream);
    hipLaunchKernelGGL(k_main, dim3(1024), dim3(64), 0, stream, xp, sigma, acc);
    hipLaunchKernelGGL(k_final, dim3((T_ * 3 * H_ * W_ + 255) / 256), dim3(256), 0, stream,
                       acc, means, out);
}

// Round 5
// 303.699 us; speedup vs baseline: 1.9541x; 1.9541x over previous
//
#include <hip/hip_runtime.h>

#define T_ 4
#define H_ 128
#define W_ 128
#define XPS 160          // padded image size (128 + 2*16)
#define WSZ 29           // search window
#define K_ 14            // neighbors kept
#define ACCS 132         // H + 2*phalf

#define SROWS 4          // pixel rows per block subtile
#define SCOLS 12         // pixel cols per block subtile
#define TR 36            // tile rows = SROWS + 32
#define TC 44            // tile cols = SCOLS + 32
#define NBI 32           // row tiles per image (128/4)
#define NBJ 11           // col tiles per image (ceil 128/12)
#define NW 4             // waves per block
#define OPW 211          // offsets per wave (ceil 841/4)

// DPP row_shl:n -> lane i reads lane i+n within its 16-lane row; OOB lanes get 0.
#define DPP_SHL(x, n) __uint_as_float((unsigned)__builtin_amdgcn_update_dpp( \
        0, (int)__float_as_uint(x), 0x100 + (n), 0xF, 0xF, true))

// ---------------- kernel 1: per-(t,c) means of normalized image ----------------
__global__ void k_means(const float* __restrict__ noisy, float* __restrict__ means) {
    int tc = blockIdx.x;                       // 0..11
    const float* src = noisy + (size_t)tc * (H_ * W_);
    float s = 0.f;
    for (int i = threadIdx.x; i < H_ * W_; i += 256) s += src[i];
    __shared__ float red[256];
    red[threadIdx.x] = s;
    __syncthreads();
    for (int st = 128; st > 0; st >>= 1) {
        if ((int)threadIdx.x < st) red[threadIdx.x] += red[threadIdx.x + st];
        __syncthreads();
    }
    if (threadIdx.x == 0)
        means[tc] = red[0] * (1.f / (H_ * W_)) * (2.f / 255.f) - 1.f;
}

// ---------------- kernel 2: reflect-pad + normalize + mean-subtract ----------------
// xp layout: [t][160][160][3] channels-last
__global__ void k_pad(const float* __restrict__ noisy, const float* __restrict__ means,
                      float* __restrict__ xp) {
    int idx = blockIdx.x * 256 + threadIdx.x;
    if (idx >= T_ * XPS * XPS) return;
    int t  = idx / (XPS * XPS);
    int rr = (idx / XPS) % XPS;
    int cc = idx % XPS;
    int ry = rr - 16; if (ry < 0) ry = -ry; if (ry > H_ - 1) ry = 2 * (H_ - 1) - ry;
    int rx = cc - 16; if (rx < 0) rx = -rx; if (rx > W_ - 1) rx = 2 * (W_ - 1) - rx;
    float* dst = xp + (size_t)idx * 3;
#pragma unroll
    for (int c = 0; c < 3; c++) {
        float v = noisy[(((size_t)t * 3 + c) * H_ + ry) * W_ + rx];
        dst[c] = v * (2.f / 255.f) - 1.f - means[t * 3 + c];
    }
}

// ---------------- kernel 3: distances + top-14 + softmax + patch scatter ----------------
// 256 threads = 4 waves per block; block owns a 4x12 pixel subtile; each wave owns
// ~211 of the 841 offsets. Inner loop: 5 ds_read_b96 + DPP horizontal sum, no barriers.
__global__ __launch_bounds__(256, 4)
void k_main(const float* __restrict__ xp, const int* __restrict__ sigma_p,
            float* __restrict__ acc) {
    __shared__ __align__(16) float tile[TR][TC][3];   // 19008 B
    __shared__ unsigned kbuf[NW * K_][49];            // 10976 B (transposed, pad 49)

    const int tid = threadIdx.x;
    const int b   = blockIdx.x;
    const int t   = b / (NBI * NBJ);
    const int rem = b % (NBI * NBJ);
    const int bi  = (rem / NBJ) * SROWS;
    const int bj  = (rem % NBJ) * SCOLS;

    // ---- stage tile: 36 rows x 33 float4 (xp rows bi..bi+35, cols bj..bj+43) ----
    const float* src = xp + ((size_t)(t * XPS + bi) * XPS + bj) * 3;
    for (int i = tid; i < TR * 33; i += 256) {
        int rr = i / 33, q = i - rr * 33;
        float4 v = *reinterpret_cast<const float4*>(src + (size_t)rr * (XPS * 3) + q * 4);
        *reinterpret_cast<float4*>(&tile[rr][0][0] + q * 4) = v;
    }
    __syncthreads();

    const int w    = tid >> 6;          // wave id 0..3
    const int lane = tid & 63;
    const int g    = lane >> 4;         // pixel row within subtile 0..3
    const int tj   = lane & 15;         // e-column 0..15 (pixel col if < 12)
    const bool valid = (tj < SCOLS) && (bj + tj < W_);

    // X0 (query-side) column cached in registers: rows g..g+4 of e-col tj
    float A[5][3];
#pragma unroll
    for (int dy = 0; dy < 5; dy++)
#pragma unroll
        for (int c = 0; c < 3; c++)
            A[dy][c] = tile[14 + g + dy][14 + tj][c];

    // top-14 packed keys: (f32 bits of d & ~0x3FF) | offset-index (unique, tie->lower o)
    unsigned keys[K_];
#pragma unroll
    for (int k = 0; k < K_; k++) keys[k] = 0xFFFFFF00u + k;
    unsigned kmax = 0xFFFFFF00u + (K_ - 1);

    const int o0 = w * OPW;
    const int on = (o0 + OPW <= WSZ * WSZ) ? OPW : (WSZ * WSZ - o0);
    for (int i = 0; i < on; i++) {
        int o  = o0 + i;
        int oy = o / WSZ;
        int ox = o - oy * WSZ;
        const float* bp = &tile[g + oy][tj + ox][0];
        float cs = 0.f;
#pragma unroll
        for (int dy = 0; dy < 5; dy++) {
            float d0 = A[dy][0] - bp[dy * (TC * 3) + 0];
            float d1 = A[dy][1] - bp[dy * (TC * 3) + 1];
            float d2 = A[dy][2] - bp[dy * (TC * 3) + 2];
            cs = cs + d0 * d0 + d1 * d1 + d2 * d2;   // column 5-sum of e
        }
        // horizontal 5-sum across e-columns via DPP (lane tj gathers tj+1..tj+4)
        float D = cs;
        D += DPP_SHL(cs, 1);
        D += DPP_SHL(cs, 2);
        D += DPP_SHL(cs, 3);
        D += DPP_SHL(cs, 4);
        unsigned key = (__float_as_uint(D) & 0xFFFFFC00u) | (unsigned)o;
        if (valid && key < kmax) {
#pragma unroll
            for (int k = 0; k < K_; k++) keys[k] = (keys[k] == kmax) ? key : keys[k];
            kmax = keys[0];
#pragma unroll
            for (int k = 1; k < K_; k++) kmax = keys[k] > kmax ? keys[k] : kmax;
        }
    }

    // ---- stash per-wave top-K (transposed: row = w*14+k, col = pixel) ----
    const int pxi = g * SCOLS + tj;     // 0..47 when valid
    if (valid) {
#pragma unroll
        for (int k = 0; k < K_; k++) kbuf[w * K_ + k][pxi] = keys[k];
    }
    // reset for merge
#pragma unroll
    for (int k = 0; k < K_; k++) keys[k] = 0xFFFFFF00u + k;
    kmax = 0xFFFFFF00u + (K_ - 1);
    __syncthreads();

    // ---- merge 4x14 candidates (each wave redundantly; register result) ----
    if (valid) {
        for (int j = 0; j < NW * K_; j++) {
            unsigned key = kbuf[j][pxi];
            if (key < kmax) {
#pragma unroll
                for (int k = 0; k < K_; k++) keys[k] = (keys[k] == kmax) ? key : keys[k];
                kmax = keys[0];
#pragma unroll
                for (int k = 1; k < K_; k++) kmax = keys[k] > kmax ? keys[k] : kmax;
            }
        }
    }

    // ---- softmax weights over merged 14 ----
    float sig  = (float)sigma_p[0] * (2.f / 255.f);
    float beta = 1.f / (2.f * sig * sig * 75.f);
    float wk[K_];
    int oyk[K_], oxk[K_];
    float dmin = 3.4e38f;
#pragma unroll
    for (int k = 0; k < K_; k++) {
        float dv = __uint_as_float(keys[k] & 0xFFFFFC00u);
        wk[k] = dv;
        int ok = (int)(keys[k] & 1023u);
        oyk[k] = ok / WSZ;
        oxk[k] = ok - oyk[k] * WSZ;
        dmin = fminf(dmin, dv);
    }
    float sw = 0.f;
#pragma unroll
    for (int k = 0; k < K_; k++) { float e = __expf(beta * (dmin - wk[k])); wk[k] = e; sw += e; }
    float inv = 1.f / sw;
#pragma unroll
    for (int k = 0; k < K_; k++) wk[k] *= inv;

    __syncthreads();                    // kbuf reads complete
    // ---- block-local overlap-add accumulator (overlays kbuf): 8 rows x 16 cols x 3 ----
    float* accb = reinterpret_cast<float*>(&kbuf[0][0]);
    for (int i = tid; i < 8 * 16 * 3; i += 256) accb[i] = 0.f;
    __syncthreads();

    // 25 patch positions split across the 4 waves
    for (int p = w; p < 25; p += NW) {
        int py = p / 5, px = p - py * 5;
        if (valid) {
            float s0 = 0.f, s1 = 0.f, s2 = 0.f;
#pragma unroll
            for (int k = 0; k < K_; k++) {
                const float* nb = &tile[g + oyk[k] + py][tj + oxk[k] + px][0];
                s0 += wk[k] * nb[0];
                s1 += wk[k] * nb[1];
                s2 += wk[k] * nb[2];
            }
            float* ap = accb + ((g + py) * 16 + (tj + px)) * 3;
            atomicAdd(ap + 0, s0);
            atomicAdd(ap + 1, s1);
            atomicAdd(ap + 2, s2);
        }
    }
    __syncthreads();

    // ---- flush block accumulator to global acc ----
    for (int i = tid; i < 8 * 16 * 3; i += 256) {
        int ch = i % 3;
        int cc = (i / 3) & 15;
        int rr = i / 48;
        int gr = bi + rr, gc = bj + cc;
        if (gc < ACCS)
            atomicAdd(&acc[(((size_t)t * ACCS + gr) * ACCS + gc) * 3 + ch], accb[i]);
    }
}

// ---------------- kernel 4: normalize by overlap count, un-normalize, write out ----------------
__global__ void k_final(const float* __restrict__ acc, const float* __restrict__ means,
                        float* __restrict__ out) {
    int idx = blockIdx.x * 256 + threadIdx.x;     // [t][ch][i][j]
    if (idx >= T_ * 3 * H_ * W_) return;
    int j  = idx & 127;
    int i  = (idx >> 7) & 127;
    int ch = (idx >> 14) % 3;
    int t  = idx / (3 * H_ * W_);
    int r = i + 2, s = j + 2;
    int ny = (r < 4 ? r : 4) - (r > 127 ? r - 127 : 0) + 1;
    int nx = (s < 4 ? s : 4) - (s > 127 ? s - 127 : 0) + 1;
    float v = acc[(((size_t)t * ACCS + r) * ACCS + s) * 3 + ch] / (float)(ny * nx);
    v += means[t * 3 + ch];
    out[idx] = 127.5f * v + 127.5f;
}

extern "C" void kernel_launch(void* const* d_in, const int* in_sizes, int n_in,
                              void* d_out, int out_size, void* d_ws, size_t ws_size,
                              hipStream_t stream) {
    (void)in_sizes; (void)n_in; (void)out_size; (void)ws_size;
    const float* noisy = (const float*)d_in[0];
    const int*   sigma = (const int*)d_in[1];

    float* means = (float*)d_ws;                         // 12 floats (reserve 64)
    float* xp    = means + 64;                           // 4*160*160*3 floats
    float* acc   = xp + (size_t)T_ * XPS * XPS * 3;      // 4*132*132*3 floats
    float* out   = (float*)d_out;

    hipLaunchKernelGGL(k_means, dim3(12), dim3(256), 0, stream, noisy, means);
    hipLaunchKernelGGL(k_pad, dim3((T_ * XPS * XPS + 255) / 256), dim3(256), 0, stream,
                       noisy, means, xp);
    hipMemsetAsync(acc, 0, (size_t)T_ * ACCS * ACCS * 3 * sizeof(float), stream);
    hipLaunchKernelGGL(k_main, dim3(T_ * NBI * NBJ), dim3(256), 0, stream, xp, sigma, acc);
    hipLaunchKernelGGL(k_final, dim3((T_ * 3 * H_ * W_ + 255) / 256), dim3(256), 0, stream,
                       acc, means, out);
}